// Round 4
// baseline (272.810 us; speedup 1.0000x reference)
//
#include <hip/hip_runtime.h>
#include <cstdint>
#include <cstddef>

using u32 = unsigned int;
using u64 = unsigned long long;

#define WROW 88        // u32 words per output-channel row in packed-weight table
#define EPSV 1e-5f

// ---------------------------------------------------------------------------
// Kernel 1: weight prep. One block per (co, conv). 256 threads = 256 in-chans.
// Row layout per co: [72 packed bit-words (pos-major, 8 words/pos)]
//                    [9 wsum ints][pad][alpha, scale, shift][pad]
// bw = sign(w - mean) (positive WS scale drops out; tau=1 -> clamp no-op).
// bn folded with IEEE ops in the reference's exact order.
// ---------------------------------------------------------------------------
__global__ void prep_weights(const float* __restrict__ w1, const float* __restrict__ w2,
                             const float* __restrict__ a1, const float* __restrict__ g1,
                             const float* __restrict__ b1, const float* __restrict__ m1,
                             const float* __restrict__ v1,
                             const float* __restrict__ a2, const float* __restrict__ g2,
                             const float* __restrict__ b2, const float* __restrict__ m2,
                             const float* __restrict__ v2,
                             u32* __restrict__ PW)
{
    const int co   = blockIdx.x;
    const int conv = blockIdx.y;
    const int c    = threadIdx.x;          // input channel
    const float* w = conv ? w2 : w1;

    float wv[9];
    const float* wp = w + ((size_t)co * 256 + c) * 9;
    float s = 0.f;
#pragma unroll
    for (int p = 0; p < 9; ++p) { wv[p] = wp[p]; s += wv[p]; }

    __shared__ float red[256];
    __shared__ int   wcount[9];
    red[c] = s;
    if (c < 9) wcount[c] = 0;
    __syncthreads();
    for (int off = 128; off > 0; off >>= 1) {
        if (c < off) red[c] += red[c + off];
        __syncthreads();
    }
    const float mean = __fdiv_rn(red[0], 2304.0f);

    u32* row = PW + ((size_t)conv * 256 + co) * WROW;
    const int wave = c >> 6, lane = c & 63;
#pragma unroll
    for (int p = 0; p < 9; ++p) {
        u64 m = __ballot(wv[p] > mean);      // bit=1 <-> +1
        if (lane == 0) {
            row[p * 8 + wave * 2]     = (u32)m;
            row[p * 8 + wave * 2 + 1] = (u32)(m >> 32);
            atomicAdd(&wcount[p], __popcll(m));
        }
    }
    __syncthreads();
    if (c < 9) row[72 + c] = (u32)(2 * wcount[c] - 256);   // wsum per position
    if (c == 0) {
        const float alpha = conv ? a2[co] : a1[co];
        const float gamma = conv ? g2[co] : g1[co];
        const float beta  = conv ? b2[co] : b1[co];
        const float mu    = conv ? m2[co] : m1[co];
        const float var   = conv ? v2[co] : v1[co];
        const float sq    = __fsqrt_rn(__fadd_rn(var, EPSV));
        const float scale = __fdiv_rn(gamma, sq);
        const float shift = __fsub_rn(beta, __fdiv_rn(__fmul_rn(mu, gamma), sq));
        row[81] = __float_as_uint(alpha);
        row[82] = __float_as_uint(scale);
        row[83] = __float_as_uint(shift);
    }
}

// ---------------------------------------------------------------------------
// Kernel 2: binarize x -> packed bits. Layout A[n][pixel][j], j = chan/32.
// ---------------------------------------------------------------------------
__global__ void binarize_x(const float* __restrict__ x, u32* __restrict__ A1)
{
    const int n = blockIdx.x >> 3;
    const int j = blockIdx.x & 7;
    const int p = threadIdx.x;              // pixel 0..1023
    const float* xp = x + (((size_t)n * 256 + j * 32) * 1024) + p;
    u32 bits = 0;
#pragma unroll
    for (int k = 0; k < 32; ++k) {
        float v = xp[(size_t)k * 1024];
        bits |= (v > 0.f ? 1u : 0u) << k;
    }
    A1[((size_t)n * 1024 + p) * 8 + j] = bits;
}

// ---------------------------------------------------------------------------
// Kernel 3/4: binary 3x3 conv via XOR+popcount.
// Grid: x = n*4 + rowtile (8 rows), y = co-quarter (64 cos).
// 256 threads = 8 rows x 32 cols; one pixel per thread, loop over 64 cos.
//
// R0-R3 lesson: the compiler keeps SINKING the 18 neighborhood loads into the
// co-loop (VGPR_Count=44 every round), re-reading 288B/lane/iter from L2
// (~4.8GB/conv -> L2-BW-bound at ~128us). Fix: pin each loaded uint4 with
// asm volatile("" : "+v"...) — a volatile asm must execute exactly once, so
// the loads cannot be cloned into the loop; the loop consumes loop-invariant
// VGPRs. Weights stream on the scalar path (wave-uniform -> s_load).
// dot = 2304 - 2*popc + sum_{halo pos} wsum[pos].
// CONV==1: emit packed sign bits of bn(conv*alpha) (hardtanh keeps sign).
// CONV==2: fp32 epilogue: bn(conv*alpha) + x, clamp to [-1,1]; coalesced I/O.
// ---------------------------------------------------------------------------
template<int CONV>
__global__ __launch_bounds__(256, 1)
void conv_bin(const u32* __restrict__ A_in, const u32* __restrict__ PW,
              const float* __restrict__ X, float* __restrict__ OUT,
              u32* __restrict__ A_out)
{
    const int n   = blockIdx.x >> 2;
    const int rt  = blockIdx.x & 3;
    const int q   = blockIdx.y;
    const int tid = threadIdx.x;
    const int pr  = tid >> 5;       // row in tile 0..7
    const int cw  = tid & 31;       // col 0..31

    const int irow = rt * 8 + pr, icol = cw;

    // 18 named act registers, predicated loads (OOB -> 0 == halo words zeroed),
    // each PINNED so the loads cannot be sunk into the co-loop.
#define LOADPOS(VA, VB, DY, DX)                                                \
    uint4 VA = make_uint4(0u,0u,0u,0u), VB = make_uint4(0u,0u,0u,0u);          \
    {   const int rr = irow + (DY) - 1, cc = icol + (DX) - 1;                  \
        if (((unsigned)rr < 32u) && ((unsigned)cc < 32u)) {                    \
            const uint4* p_ = (const uint4*)(A_in +                            \
                (((size_t)n * 1024 + rr * 32 + cc) * 8));                      \
            VA = p_[0]; VB = p_[1];                                            \
        }                                                                      \
        asm volatile("" : "+v"(VA.x), "+v"(VA.y), "+v"(VA.z), "+v"(VA.w));     \
        asm volatile("" : "+v"(VB.x), "+v"(VB.y), "+v"(VB.z), "+v"(VB.w));     \
    }

    LOADPOS(a00A, a00B, 0, 0)
    LOADPOS(a01A, a01B, 0, 1)
    LOADPOS(a02A, a02B, 0, 2)
    LOADPOS(a10A, a10B, 1, 0)
    LOADPOS(a11A, a11B, 1, 1)
    LOADPOS(a12A, a12B, 1, 2)
    LOADPOS(a20A, a20B, 2, 0)
    LOADPOS(a21A, a21B, 2, 1)
    LOADPOS(a22A, a22B, 2, 2)
#undef LOADPOS

    u32 hm = 0;
#pragma unroll
    for (int dy = 0; dy < 3; ++dy)
#pragma unroll
        for (int dx = 0; dx < 3; ++dx) {
            int rr = irow + dy - 1, cc = icol + dx - 1;
            if (rr < 0 || rr >= 32 || cc < 0 || cc >= 32) hm |= 1u << (dy * 3 + dx);
        }

    const u32* PWq = PW + ((size_t)((CONV == 2) ? 256 : 0) + q * 64) * WROW;

    u64 ow = 0;
#pragma unroll 1
    for (int i = 0; i < 64; ++i) {
        const u32* row = PWq + (size_t)i * WROW;     // wave-uniform -> s_load
        const uint4* row4 = (const uint4*)row;
        u32 s0 = 0, s1 = 0, s2 = 0, s3 = 0, s4 = 0, s5 = 0, s6 = 0, s7 = 0;
#define ACC(P, AA, AB) do {                                                    \
        const uint4 wa = row4[(P) * 2];                                        \
        const uint4 wb = row4[(P) * 2 + 1];                                    \
        s0 += __popc(AA.x ^ wa.x);  s1 += __popc(AA.y ^ wa.y);                 \
        s2 += __popc(AA.z ^ wa.z);  s3 += __popc(AA.w ^ wa.w);                 \
        s4 += __popc(AB.x ^ wb.x);  s5 += __popc(AB.y ^ wb.y);                 \
        s6 += __popc(AB.z ^ wb.z);  s7 += __popc(AB.w ^ wb.w); } while (0)
        ACC(0, a00A, a00B);
        ACC(1, a01A, a01B);
        ACC(2, a02A, a02B);
        ACC(3, a10A, a10B);
        ACC(4, a11A, a11B);
        ACC(5, a12A, a12B);
        ACC(6, a20A, a20B);
        ACC(7, a21A, a21B);
        ACC(8, a22A, a22B);
#undef ACC
        const int P = (int)(((s0 + s1) + (s2 + s3)) + ((s4 + s5) + (s6 + s7)));
        int corr = 0;
        if (hm) {
#pragma unroll
            for (int p = 0; p < 9; ++p)
                if ((hm >> p) & 1) corr += (int)row[72 + p];
        }
        const int dot = 2304 - 2 * P + corr;

        const float alpha = __uint_as_float(row[81]);
        const float scale = __uint_as_float(row[82]);
        const float shift = __uint_as_float(row[83]);
        // match reference rounding: (conv*alpha) then *scale then +shift, no fma
        const float t = __fadd_rn(__fmul_rn(__fmul_rn((float)dot, alpha), scale), shift);

        if (CONV == 1) {
            ow |= (u64)(t > 0.f ? 1u : 0u) << i;
        } else {
            const int co = q * 64 + i;
            const size_t idx = (((size_t)n * 256 + co) * 1024) + (size_t)irow * 32 + icol;
            float y = __fadd_rn(t, X[idx]);
            y = fminf(1.0f, fmaxf(-1.0f, y));
            OUT[idx] = y;
        }
    }
    if (CONV == 1) {
        const size_t base = (((size_t)n * 1024) + (size_t)irow * 32 + icol) * 8 + q * 2;
        A_out[base]     = (u32)ow;
        A_out[base + 1] = (u32)(ow >> 32);
    }
}

// ---------------------------------------------------------------------------
extern "C" void kernel_launch(void* const* d_in, const int* in_sizes, int n_in,
                              void* d_out, int out_size, void* d_ws, size_t ws_size,
                              hipStream_t stream)
{
    const float* x   = (const float*)d_in[0];
    const float* w1  = (const float*)d_in[1];
    const float* al1 = (const float*)d_in[2];
    const float* g1  = (const float*)d_in[3];
    const float* b1  = (const float*)d_in[4];
    const float* m1  = (const float*)d_in[5];
    const float* v1  = (const float*)d_in[6];
    const float* w2  = (const float*)d_in[7];
    const float* al2 = (const float*)d_in[8];
    const float* g2  = (const float*)d_in[9];
    const float* b2  = (const float*)d_in[10];
    const float* m2  = (const float*)d_in[11];
    const float* v2  = (const float*)d_in[12];
    float* out = (float*)d_out;

    u32* PW = (u32*)d_ws;                               // 2*256*88*4 = 180 KB
    u32* A1 = (u32*)((char*)d_ws + (1u << 20));         // 2 MB packed sign(x)
    u32* A2 = (u32*)((char*)d_ws + 3u * (1u << 20));    // 2 MB packed layer-1 signs
    (void)ws_size; (void)in_sizes; (void)n_in; (void)out_size;

    prep_weights<<<dim3(256, 2), 256, 0, stream>>>(w1, w2, al1, g1, b1, m1, v1,
                                                   al2, g2, b2, m2, v2, PW);
    binarize_x<<<dim3(512), 1024, 0, stream>>>(x, A1);
    conv_bin<1><<<dim3(256, 4), 256, 0, stream>>>(A1, PW, nullptr, nullptr, A2);
    conv_bin<2><<<dim3(256, 4), 256, 0, stream>>>(A2, PW, x, out, nullptr);
}

// Round 5
// 138.007 us; speedup vs baseline: 1.9768x; 1.9768x over previous
//
#include <hip/hip_runtime.h>
#include <cstdint>
#include <cstddef>

using u32 = unsigned int;
using u64 = unsigned long long;

typedef int v4i  __attribute__((ext_vector_type(4)));
typedef int v16i __attribute__((ext_vector_type(16)));

#define EPSV 1e-5f

// ---------------------------------------------------------------------------
// Kernel 1: weight prep. One block per (co, conv). 256 threads = 256 in-chans.
// Outputs:
//   Wsgn[conv][co][p][c] i8 = sign(w - mean)  (+1 -> 0x01, -1 -> 0xFF)
//   SC4[conv*256+co] = float4(alpha, scale, shift, 0) with IEEE ops in the
//   reference's exact order.
// ---------------------------------------------------------------------------
__global__ void prep_weights(const float* __restrict__ w1, const float* __restrict__ w2,
                             const float* __restrict__ a1, const float* __restrict__ g1,
                             const float* __restrict__ b1, const float* __restrict__ m1,
                             const float* __restrict__ v1,
                             const float* __restrict__ a2, const float* __restrict__ g2,
                             const float* __restrict__ b2, const float* __restrict__ m2,
                             const float* __restrict__ v2,
                             unsigned char* __restrict__ Wsgn, float4* __restrict__ SC4)
{
    const int co   = blockIdx.x;
    const int conv = blockIdx.y;
    const int c    = threadIdx.x;          // input channel
    const float* w = conv ? w2 : w1;

    float wv[9];
    const float* wp = w + ((size_t)co * 256 + c) * 9;
    float s = 0.f;
#pragma unroll
    for (int p = 0; p < 9; ++p) { wv[p] = wp[p]; s += wv[p]; }

    __shared__ float red[256];
    red[c] = s;
    __syncthreads();
    for (int off = 128; off > 0; off >>= 1) {
        if (c < off) red[c] += red[c + off];
        __syncthreads();
    }
    const float mean = __fdiv_rn(red[0], 2304.0f);

    unsigned char* wrow = Wsgn + ((size_t)(conv * 256 + co) * 9) * 256;
#pragma unroll
    for (int p = 0; p < 9; ++p)
        wrow[p * 256 + c] = (wv[p] > mean) ? 0x01u : 0xFFu;

    if (c == 0) {
        const float alpha = conv ? a2[co] : a1[co];
        const float gamma = conv ? g2[co] : g1[co];
        const float beta  = conv ? b2[co] : b1[co];
        const float mu    = conv ? m2[co] : m1[co];
        const float var   = conv ? v2[co] : v1[co];
        const float sq    = __fsqrt_rn(__fadd_rn(var, EPSV));
        const float scale = __fdiv_rn(gamma, sq);
        const float shift = __fsub_rn(beta, __fdiv_rn(__fmul_rn(mu, gamma), sq));
        SC4[conv * 256 + co] = make_float4(alpha, scale, shift, 0.f);
    }
}

// ---------------------------------------------------------------------------
// Kernel 2: build B fragments in exact mfma_i32_32x32x32_i8 operand order.
// Frag f = conv*576 + g*72 + p*8 + cb  (g: co-group of 32, p: 3x3 pos,
// cb: channel-block of 32). Lane l holds B[k=(l>>5)*16+j][n=l&31]:
// 16 consecutive channel bytes -> one uint4 copy from Wsgn.
// ---------------------------------------------------------------------------
__global__ void build_bfrag(const unsigned char* __restrict__ Wsgn, uint4* __restrict__ Bf)
{
    const int f    = blockIdx.x;           // 0..1151
    const int lane = threadIdx.x;          // 0..63
    const int conv = f / 576;
    const int rem  = f % 576;
    const int g    = rem / 72;
    const int p    = (rem % 72) / 8;
    const int cb   = rem % 8;
    const int co   = g * 32 + (lane & 31);
    const unsigned char* src = Wsgn + ((size_t)(conv * 256 + co) * 9 + p) * 256
                                    + cb * 32 + (lane >> 5) * 16;
    Bf[(size_t)f * 64 + lane] = *(const uint4*)src;
}

// ---------------------------------------------------------------------------
// Kernel 3: binarize x -> packed bits. Layout A[n][pixel][j], j = chan/32.
// ---------------------------------------------------------------------------
__global__ void binarize_x(const float* __restrict__ x, u32* __restrict__ A1)
{
    const int n = blockIdx.x >> 3;
    const int j = blockIdx.x & 7;
    const int p = threadIdx.x;              // pixel 0..1023
    const float* xp = x + (((size_t)n * 256 + j * 32) * 1024) + p;
    u32 bits = 0;
#pragma unroll
    for (int k = 0; k < 32; ++k) {
        float v = xp[(size_t)k * 1024];
        bits |= (v > 0.f ? 1u : 0u) << k;
    }
    A1[((size_t)n * 1024 + p) * 8 + j] = bits;
}

// expand 4 bits -> 4 i8 bytes (+1 -> 0x01, -1 -> 0xFF)
__device__ __forceinline__ u32 expand4(u32 x)
{
    u32 r;
    r  = ((x & 1u) ? 0x00000001u : 0x000000FFu);
    r |= ((x & 2u) ? 0x00000100u : 0x0000FF00u);
    r |= ((x & 4u) ? 0x00010000u : 0x00FF0000u);
    r |= ((x & 8u) ? 0x01000000u : 0xFF000000u);
    return r;
}

// ---------------------------------------------------------------------------
// Kernel 4/5: binary conv as i8 MFMA GEMM.
// Block: 256 thr = 4 waves. Covers 2 output rows (y0,y0+1) x 128 cos
// (q = co-half). Wave w handles co-group g = q*4+w (32 cos) for BOTH rows.
// grid = (64 n * 16 ypairs, 2).
//
// LDS: i8 tile rows y0-1..y0+2 (4), cols -1..32 (34), 256 ch = 34816 B,
// XOR-swizzled by ^((x&7)<<4) to kill the stride-256 bank conflict.
// Staged by unpacking packed sign bits (halo -> 0x00: zero-padding becomes
// genuine zero MACs -> no halo corrections, dot is the conv sum directly).
//
// K-loop: 9 pos x 8 ch-blocks: load B frag (global, coalesced 16B/lane),
// 2x ds_read_b128 A frags (rows dy, dy+1), 2x mfma_i32_32x32x32_i8.
// Fragment maps: A: m=l&31 (=x), k=(l>>5)*16+j; B: n=l&31 (=co), same k;
// C/D: n=l&31, m=(reg&3)+8*(reg>>2)+4*(l>>5)   [m74/m101-verified].
//
// CONV==1 epilogue: t = (dot*alpha)*scale+shift; sign bits via __ballot —
// lanes are co-ordered so lo word = 32 co-bits at x=m0, hi word at x=m0+4;
// lane 0 stores both into the packed A2 image.
// CONV==2 epilogue: stage t into LDS as ep[yy][x][co] (conflict-free),
// then 256 threads write coalesced NCHW runs: clamp(t + X) -> OUT.
// ---------------------------------------------------------------------------
template<int CONV>
__global__ __launch_bounds__(256, 2)
void conv_mfma(const u32* __restrict__ A_in, const v4i* __restrict__ Bf,
               const float4* __restrict__ SC4, const float* __restrict__ X,
               u32* __restrict__ A_out, float* __restrict__ OUT)
{
    const int n    = blockIdx.x >> 4;
    const int yp   = blockIdx.x & 15;
    const int q    = blockIdx.y;            // co half (128 cos)
    const int tid  = threadIdx.x;
    const int wave = tid >> 6;
    const int lane = tid & 63;
    const int y0   = yp * 2;

    __shared__ alignas(16) unsigned char lds[34816];

    // ---- stage: packed bits -> swizzled i8 tile ----
    for (int s = tid; s < 2176; s += 256) {
        const int r   = s / 544;            // lds row 0..3  (image row y0-1+r)
        const int rm  = s - r * 544;
        const int xs  = rm >> 4;            // stored col 0..33 (image x = xs-1)
        const int c16 = rm & 15;            // 16-channel group
        const int iy  = y0 - 1 + r;
        const int ix  = xs - 1;
        u32 d0 = 0, d1 = 0, d2 = 0, d3 = 0;
        if ((unsigned)iy < 32u && (unsigned)ix < 32u) {
            const u32 wrd = A_in[((size_t)n * 1024 + iy * 32 + ix) * 8 + (c16 >> 1)];
            const u32 h = (wrd >> ((c16 & 1) * 16)) & 0xFFFFu;
            d0 = expand4(h);
            d1 = expand4(h >> 4);
            d2 = expand4(h >> 8);
            d3 = expand4(h >> 12);
        }
        const u32 off = ((u32)((r * 34 + xs) * 256 + c16 * 16)) ^ ((u32)(xs & 7) << 4);
        *(uint4*)(lds + off) = make_uint4(d0, d1, d2, d3);
    }
    __syncthreads();

    // ---- K-loop ----
    v16i acc0 = {0,0,0,0,0,0,0,0,0,0,0,0,0,0,0,0};
    v16i acc1 = {0,0,0,0,0,0,0,0,0,0,0,0,0,0,0,0};
    const int g = q * 4 + wave;
    const v4i* Bq = Bf + ((size_t)(((CONV == 2) ? 576 : 0) + g * 72)) * 64 + lane;

#pragma unroll
    for (int p = 0; p < 9; ++p) {
        const int dy = p / 3, dx = p % 3;
        const u32 xs  = (u32)(lane & 31) + (u32)dx;
        const u32 swz = (xs & 7u) << 4;
        const u32 raw = (u32)((dy * 34 + xs) * 256) + (u32)((lane >> 5) * 16);
#pragma unroll
        for (int cb = 0; cb < 8; ++cb) {
            const v4i b  = Bq[(p * 8 + cb) * 64];
            const u32 o0 = (raw + (u32)(cb * 32)) ^ swz;
            const v4i a0 = *(const v4i*)(lds + o0);
            const v4i a1 = *(const v4i*)(lds + o0 + 8704);
            acc0 = __builtin_amdgcn_mfma_i32_32x32x32_i8(a0, b, acc0, 0, 0, 0);
            acc1 = __builtin_amdgcn_mfma_i32_32x32x32_i8(a1, b, acc1, 0, 0, 0);
        }
    }

    // per-lane epilogue constants (co = g*32 + (lane&31))
    const float4 sc = SC4[((CONV == 2) ? 256 : 0) + q * 128 + wave * 32 + (lane & 31)];
    const float alpha = sc.x, scale = sc.y, shift = sc.z;

    if (CONV == 1) {
#define EPILOG1(ACC, YY)                                                        \
        _Pragma("unroll")                                                       \
        for (int reg = 0; reg < 16; ++reg) {                                    \
            const int dot = ACC[reg];                                           \
            const float t = __fadd_rn(__fmul_rn(__fmul_rn((float)dot, alpha),   \
                                                scale), shift);                 \
            const u64 m = __ballot(t > 0.f);                                    \
            const int m0 = (reg & 3) + 8 * (reg >> 2);                          \
            if (lane == 0) {                                                    \
                const size_t pbase = (size_t)n * 1024 + (y0 + (YY)) * 32;       \
                A_out[(pbase + m0) * 8 + g]     = (u32)m;                       \
                A_out[(pbase + m0 + 4) * 8 + g] = (u32)(m >> 32);               \
            }                                                                   \
        }
        EPILOG1(acc0, 0)
        EPILOG1(acc1, 1)
#undef EPILOG1
    } else {
        __syncthreads();                    // done reading act tile
        float* ep = (float*)lds;            // ep[yy][x][co128] = 32 KB
        const int co_l = wave * 32 + (lane & 31);
#define EPILOG2(ACC, YY)                                                        \
        _Pragma("unroll")                                                       \
        for (int reg = 0; reg < 16; ++reg) {                                    \
            const int dot = ACC[reg];                                           \
            const float t = __fadd_rn(__fmul_rn(__fmul_rn((float)dot, alpha),   \
                                                scale), shift);                 \
            const int xx = (reg & 3) + 8 * (reg >> 2) + 4 * (lane >> 5);        \
            ep[((YY) * 32 + xx) * 128 + co_l] = t;                              \
        }
        EPILOG2(acc0, 0)
        EPILOG2(acc1, 1)
#undef EPILOG2
        __syncthreads();

        const int co = tid & 127, yy = tid >> 7;
        const size_t base = ((size_t)(n * 256 + q * 128 + co)) * 1024 + (y0 + yy) * 32;
#pragma unroll
        for (int x4 = 0; x4 < 32; x4 += 4) {
            float4 r;
            r.x = ep[(yy * 32 + x4 + 0) * 128 + co];
            r.y = ep[(yy * 32 + x4 + 1) * 128 + co];
            r.z = ep[(yy * 32 + x4 + 2) * 128 + co];
            r.w = ep[(yy * 32 + x4 + 3) * 128 + co];
            const float4 xv = *(const float4*)(X + base + x4);
            r.x = fminf(1.0f, fmaxf(-1.0f, __fadd_rn(r.x, xv.x)));
            r.y = fminf(1.0f, fmaxf(-1.0f, __fadd_rn(r.y, xv.y)));
            r.z = fminf(1.0f, fmaxf(-1.0f, __fadd_rn(r.z, xv.z)));
            r.w = fminf(1.0f, fmaxf(-1.0f, __fadd_rn(r.w, xv.w)));
            *(float4*)(OUT + base + x4) = r;
        }
    }
}

// ---------------------------------------------------------------------------
extern "C" void kernel_launch(void* const* d_in, const int* in_sizes, int n_in,
                              void* d_out, int out_size, void* d_ws, size_t ws_size,
                              hipStream_t stream)
{
    const float* x   = (const float*)d_in[0];
    const float* w1  = (const float*)d_in[1];
    const float* al1 = (const float*)d_in[2];
    const float* g1  = (const float*)d_in[3];
    const float* b1  = (const float*)d_in[4];
    const float* m1  = (const float*)d_in[5];
    const float* v1  = (const float*)d_in[6];
    const float* w2  = (const float*)d_in[7];
    const float* al2 = (const float*)d_in[8];
    const float* g2  = (const float*)d_in[9];
    const float* b2  = (const float*)d_in[10];
    const float* m2  = (const float*)d_in[11];
    const float* v2  = (const float*)d_in[12];
    float* out = (float*)d_out;

    char* ws = (char*)d_ws;
    float4*        SC4  = (float4*)(ws);                    //   8 KB
    unsigned char* Wsgn = (unsigned char*)(ws + (64u << 10));   // 1.18 MB
    uint4*         Bf   = (uint4*)(ws + (2u << 20));        // 1.18 MB
    u32*           A1   = (u32*)(ws + (4u << 20));          // 2 MB packed sign(x)
    u32*           A2   = (u32*)(ws + (6u << 20));          // 2 MB packed layer-1 signs
    (void)ws_size; (void)in_sizes; (void)n_in; (void)out_size;

    prep_weights<<<dim3(256, 2), 256, 0, stream>>>(w1, w2, al1, g1, b1, m1, v1,
                                                   al2, g2, b2, m2, v2, Wsgn, SC4);
    build_bfrag<<<dim3(1152), 64, 0, stream>>>(Wsgn, Bf);
    binarize_x<<<dim3(512), 1024, 0, stream>>>(x, A1);
    conv_mfma<1><<<dim3(1024, 2), 256, 0, stream>>>(A1, (const v4i*)Bf, SC4,
                                                    nullptr, A2, nullptr);
    conv_mfma<2><<<dim3(1024, 2), 256, 0, stream>>>(A2, (const v4i*)Bf, SC4,
                                                    x, nullptr, out);
}